// Round 5
// baseline (1760.148 us; speedup 1.0000x reference)
//
#include <hip/hip_runtime.h>
#include <hip/hip_bf16.h>

#define N_USERS 100000
#define N_ITEMS 150000
#define N_NODES 250000
#define N_EDGES 4000000
#define DIM     64
#define N_ELEM  (N_NODES * DIM)      // 16,000,000
#define U_ELEM  (N_USERS * DIM)      //  6,400,000
#define SCAN_BS 256
#define SCAN_NB ((N_NODES + SCAN_BS - 1) / SCAN_BS)   // 977
#define BSHIFT  8
#define NBUCKET ((N_NODES + (1 << BSHIFT) - 1) >> BSHIFT)  // 977

struct alignas(8) Edge { int src; float val; };
struct Edge3 { int src; float val; int dst; };   // 12 B pass-A record

// ---------------- helpers ----------------
__device__ __forceinline__ void  store_x(float* p, float v)          { *p = v; }
__device__ __forceinline__ void  store_x(__hip_bfloat16* p, float v) { *p = __float2bfloat16(v); }
__device__ __forceinline__ float load_x(const float* p)              { return *p; }
__device__ __forceinline__ float load_x(const __hip_bfloat16* p)     { return __bfloat162float(*p); }

// ---------------- dtype probe (flag=1 -> bf16 inputs, 0 -> fp32) ----------------
__global__ void probe_dtype(const unsigned short* __restrict__ ue, int* __restrict__ flag) {
    int lane = threadIdx.x;   // 64 threads
    int bad = 0;
    #pragma unroll
    for (int k = 0; k < 8; ++k) {
        unsigned int b = ((unsigned int)ue[lane * 8 + k]) << 16;
        float f = fabsf(__uint_as_float(b));
        if (!(f < 1.0f)) bad = 1;
    }
    unsigned long long m = __ballot(bad);
    if (lane == 0) flag[0] = (m == 0ULL) ? 1 : 0;
}

// ---------------- CSR build ----------------
__global__ void hist_kernel(const int* __restrict__ dst, int* __restrict__ row_ptr) {
    int e = blockIdx.x * blockDim.x + threadIdx.x;
    if (e < N_EDGES) atomicAdd(&row_ptr[dst[e] + 1], 1);
}

__global__ void scan_block(int* __restrict__ a, int* __restrict__ bsums) {
    __shared__ int sh[SCAN_BS];
    int gid = blockIdx.x * SCAN_BS + threadIdx.x;
    sh[threadIdx.x] = (gid < N_NODES) ? a[gid] : 0;
    __syncthreads();
    for (int off = 1; off < SCAN_BS; off <<= 1) {
        int t = (threadIdx.x >= off) ? sh[threadIdx.x - off] : 0;
        __syncthreads();
        sh[threadIdx.x] += t;
        __syncthreads();
    }
    if (gid < N_NODES) a[gid] = sh[threadIdx.x];
    if (threadIdx.x == SCAN_BS - 1) bsums[blockIdx.x] = sh[threadIdx.x];
}

__global__ void scan_tops(int* __restrict__ bsums) {
    __shared__ int sh[1024];
    sh[threadIdx.x] = (threadIdx.x < SCAN_NB) ? bsums[threadIdx.x] : 0;
    __syncthreads();
    for (int off = 1; off < 1024; off <<= 1) {
        int t = (threadIdx.x >= off) ? sh[threadIdx.x - off] : 0;
        __syncthreads();
        sh[threadIdx.x] += t;
        __syncthreads();
    }
    if (threadIdx.x < SCAN_NB) bsums[threadIdx.x] = sh[threadIdx.x];
}

// finalize row_ptr and init per-dst cursor
__global__ void finalize_rows(int* __restrict__ row_ptr, const int* __restrict__ bsums,
                              int* __restrict__ cursor) {
    int i = blockIdx.x * blockDim.x + threadIdx.x;
    if (i >= N_NODES) return;
    int b = i / SCAN_BS;
    int v = row_ptr[i + 1];
    if (b > 0) v += bsums[b - 1];
    row_ptr[i + 1] = v;
    if (i + 1 < N_NODES) cursor[i + 1] = v;
    if (i == 0) { row_ptr[0] = 0; cursor[0] = 0; }
}

// per-bucket cursor = row_ptr[b<<BSHIFT]
__global__ void init_bcur(const int* __restrict__ row_ptr, int* __restrict__ bcur) {
    int b = blockIdx.x * blockDim.x + threadIdx.x;
    if (b < NBUCKET) bcur[b] = row_ptr[b << BSHIFT];
}

// ---- pass A: append {src,val,dst} to dst-bucket (appends are L2-line friendly) ----
__global__ void bucket_scatter(const int* __restrict__ src, const int* __restrict__ dst,
                               const void* __restrict__ valsv, const int* __restrict__ flag,
                               int* __restrict__ bcur, Edge3* __restrict__ aux) {
    int e = blockIdx.x * blockDim.x + threadIdx.x;
    if (e >= N_EDGES) return;
    int d = dst[e];
    int b = d >> BSHIFT;
    int pos = atomicAdd(&bcur[b], 1);
    float v = (*flag) ? __bfloat162float(((const __hip_bfloat16*)valsv)[e])
                      : ((const float*)valsv)[e];
    Edge3 r; r.src = src[e]; r.val = v; r.dst = d;
    aux[pos] = r;
}

// ---- pass B: one block per bucket; re-scatter into exact CSR order (L2-local) ----
__global__ void csr_scatter(const int* __restrict__ row_ptr, int* __restrict__ cursor,
                            const Edge3* __restrict__ aux, Edge* __restrict__ sedge) {
    int b = blockIdx.x;
    int n0 = b << BSHIFT;
    int n1 = (b + 1) << BSHIFT; if (n1 > N_NODES) n1 = N_NODES;
    int lo = row_ptr[n0], hi = row_ptr[n1];
    for (int e = lo + threadIdx.x; e < hi; e += blockDim.x) {
        Edge3 r = aux[e];
        int pos = atomicAdd(&cursor[r.dst], 1);
        Edge o; o.src = r.src; o.val = r.val;
        sedge[pos] = o;
    }
}

// ---------------- init: x = concat(user,item); acc (T1) or out-acc (T2/T3) ----------------
template <typename XT>
__global__ void init_kernel(const void* __restrict__ uev, const void* __restrict__ iev,
                            const int* __restrict__ flag,
                            XT* __restrict__ x,
                            float* __restrict__ acc,
                            void* __restrict__ outacc) {
    int i = blockIdx.x * blockDim.x + threadIdx.x;
    if (i >= N_ELEM) return;
    const int isbf = *flag;
    float v;
    if (i < U_ELEM) {
        v = isbf ? __bfloat162float(((const __hip_bfloat16*)uev)[i]) : ((const float*)uev)[i];
    } else {
        int j = i - U_ELEM;
        v = isbf ? __bfloat162float(((const __hip_bfloat16*)iev)[j]) : ((const float*)iev)[j];
    }
    store_x(&x[i], v);
    if (acc) acc[i] = v;
    if (outacc) {
        if (isbf) ((__hip_bfloat16*)outacc)[i] = __float2bfloat16(0.25f * v);
        else      ((float*)outacc)[i]          = 0.25f * v;
    }
}

// ---------------- CSR SpMM: one wave per dst node, lane = dim ----------------
template <typename XT>
__global__ void spmm_csr(const int* __restrict__ row_ptr,
                         const Edge* __restrict__ sedge,
                         const XT* __restrict__ x,
                         XT* __restrict__ xn,
                         float* __restrict__ acc,      // T1 mode if non-null
                         void* __restrict__ outv,      // T2/T3 RMW target, or T1 final target
                         const int* __restrict__ flag,
                         int last) {
    int lane = threadIdx.x & 63;
    int w = (blockIdx.x * blockDim.x + threadIdx.x) >> 6;
    if (w >= N_NODES) return;
    int beg = row_ptr[w], end = row_ptr[w + 1];
    float s = 0.f;
    int e = beg;
    for (; e + 4 <= end; e += 4) {
        Edge e0 = sedge[e], e1 = sedge[e + 1], e2 = sedge[e + 2], e3 = sedge[e + 3];
        float a0 = load_x(&x[(size_t)e0.src * DIM + lane]);
        float a1 = load_x(&x[(size_t)e1.src * DIM + lane]);
        float a2 = load_x(&x[(size_t)e2.src * DIM + lane]);
        float a3 = load_x(&x[(size_t)e3.src * DIM + lane]);
        s += e0.val * a0; s += e1.val * a1; s += e2.val * a2; s += e3.val * a3;
    }
    for (; e < end; ++e) {
        Edge ee = sedge[e];
        s += ee.val * load_x(&x[(size_t)ee.src * DIM + lane]);
    }

    size_t o = (size_t)w * DIM + lane;
    if (acc) {
        if (!last) {
            store_x(&xn[o], s);
            acc[o] += s;
        } else {
            float r = 0.25f * (acc[o] + s);
            if (*flag) ((__hip_bfloat16*)outv)[o] = __float2bfloat16(r);
            else       ((float*)outv)[o]          = r;
        }
    } else {
        if (!last) store_x(&xn[o], s);
        if (*flag) {
            __hip_bfloat16* ob = (__hip_bfloat16*)outv;
            ob[o] = __float2bfloat16(__bfloat162float(ob[o]) + 0.25f * s);
        } else {
            float* of = (float*)outv;
            of[o] += 0.25f * s;
        }
    }
}

// ---------------- host ----------------
static inline size_t align256(size_t x) { return (x + 255) & ~(size_t)255; }

extern "C" void kernel_launch(void* const* d_in, const int* in_sizes, int n_in,
                              void* d_out, int out_size, void* d_ws, size_t ws_size,
                              hipStream_t stream) {
    const int* es = (const int*)d_in[3];
    const int* ed = (const int*)d_in[4];

    char* wsb = (char*)d_ws;
    size_t off = 0;
    int* flag    = (int*)wsb;                 off = align256(off + sizeof(int));
    int* row_ptr = (int*)(wsb + off);         off = align256(off + (size_t)(N_NODES + 1) * 4);
    int* cursor  = (int*)(wsb + off);         off = align256(off + (size_t)N_NODES * 4);
    int* bsums   = (int*)(wsb + off);         off = align256(off + (size_t)SCAN_NB * 4);
    int* bcur    = (int*)(wsb + off);         off = align256(off + (size_t)NBUCKET * 4);
    Edge* sedge  = (Edge*)(wsb + off);        off = align256(off + (size_t)N_EDGES * sizeof(Edge));
    size_t buf_off = off;
    // aux (48 MB) aliases the x/xn/acc block: everything there is written
    // only AFTER csr_scatter completes (stream-ordered), so no extra ws.
    Edge3* aux = (Edge3*)(wsb + buf_off);

    const size_t f32buf = (size_t)N_ELEM * sizeof(float);          // 64 MB

    const int eb = 256;
    const int egrid = (N_ELEM + eb - 1) / eb;
    const int ggrid = (N_EDGES + eb - 1) / eb;            // 15625
    const int ngrid = (N_NODES + eb - 1) / eb;            // 977
    const int sgrid = (N_NODES + 3) / 4;                  // 62500 blocks, 4 waves each

    // ---- prologue: probe + CSR build (two-pass radix scatter) ----
    probe_dtype<<<1, 64, 0, stream>>>((const unsigned short*)d_in[0], flag);
    hipMemsetAsync(row_ptr, 0, (size_t)(N_NODES + 1) * 4, stream);
    hist_kernel<<<ggrid, eb, 0, stream>>>(ed, row_ptr);
    scan_block<<<SCAN_NB, SCAN_BS, 0, stream>>>(row_ptr + 1, bsums);
    scan_tops<<<1, 1024, 0, stream>>>(bsums);
    finalize_rows<<<ngrid, eb, 0, stream>>>(row_ptr, bsums, cursor);
    init_bcur<<<(NBUCKET + eb - 1) / eb, eb, 0, stream>>>(row_ptr, bcur);
    bucket_scatter<<<ggrid, eb, 0, stream>>>(es, ed, d_in[2], flag, bcur, aux);
    csr_scatter<<<NBUCKET, eb, 0, stream>>>(row_ptr, cursor, aux, sedge);

    size_t need_t1 = buf_off + 3 * f32buf;   // ~226 MB
    size_t need_t2 = buf_off + 2 * f32buf;   // ~162 MB

    if (ws_size >= need_t1) {
        // T1: fp32 x, xn, acc; out written by last spmm
        float* x   = (float*)(wsb + buf_off);
        float* xn  = x + N_ELEM;
        float* acc = xn + N_ELEM;
        init_kernel<float><<<egrid, eb, 0, stream>>>(d_in[0], d_in[1], flag, x, acc, nullptr);
        spmm_csr<float><<<sgrid, eb, 0, stream>>>(row_ptr, sedge, x,  xn, acc, nullptr, flag, 0);
        spmm_csr<float><<<sgrid, eb, 0, stream>>>(row_ptr, sedge, xn, x,  acc, nullptr, flag, 0);
        spmm_csr<float><<<sgrid, eb, 0, stream>>>(row_ptr, sedge, x,  xn, acc, d_out,   flag, 1);
    } else if (ws_size >= need_t2) {
        // T2: fp32 x, xn; accumulate into d_out (RMW)
        float* x  = (float*)(wsb + buf_off);
        float* xn = x + N_ELEM;
        init_kernel<float><<<egrid, eb, 0, stream>>>(d_in[0], d_in[1], flag, x, nullptr, d_out);
        spmm_csr<float><<<sgrid, eb, 0, stream>>>(row_ptr, sedge, x,  xn, nullptr, d_out, flag, 0);
        spmm_csr<float><<<sgrid, eb, 0, stream>>>(row_ptr, sedge, xn, x,  nullptr, d_out, flag, 0);
        spmm_csr<float><<<sgrid, eb, 0, stream>>>(row_ptr, sedge, x,  xn, nullptr, d_out, flag, 1);
    } else {
        // T3: bf16 x, xn; accumulate into d_out (RMW)
        __hip_bfloat16* x  = (__hip_bfloat16*)(wsb + buf_off);
        __hip_bfloat16* xn = x + N_ELEM;
        init_kernel<__hip_bfloat16><<<egrid, eb, 0, stream>>>(d_in[0], d_in[1], flag, x, nullptr, d_out);
        spmm_csr<__hip_bfloat16><<<sgrid, eb, 0, stream>>>(row_ptr, sedge, x,  xn, nullptr, d_out, flag, 0);
        spmm_csr<__hip_bfloat16><<<sgrid, eb, 0, stream>>>(row_ptr, sedge, xn, x,  nullptr, d_out, flag, 0);
        spmm_csr<__hip_bfloat16><<<sgrid, eb, 0, stream>>>(row_ptr, sedge, x,  xn, nullptr, d_out, flag, 1);
    }
}

// Round 6
// 1075.921 us; speedup vs baseline: 1.6359x; 1.6359x over previous
//
#include <hip/hip_runtime.h>
#include <hip/hip_bf16.h>

#define N_USERS 100000
#define N_ITEMS 150000
#define N_NODES 250000
#define N_EDGES 4000000
#define DIM     64
#define N_ELEM  (N_NODES * DIM)      // 16,000,000
#define U_ELEM  (N_USERS * DIM)      //  6,400,000
#define SCAN_BS 256
#define SCAN_NB ((N_NODES + SCAN_BS - 1) / SCAN_BS)   // 977

// ---------------- dtype probe (flag=1 -> bf16 inputs, 0 -> fp32) ----------------
__global__ void probe_dtype(const unsigned short* __restrict__ ue, int* __restrict__ flag) {
    int lane = threadIdx.x;   // 64 threads
    int bad = 0;
    #pragma unroll
    for (int k = 0; k < 8; ++k) {
        unsigned int b = ((unsigned int)ue[lane * 8 + k]) << 16;
        float f = fabsf(__uint_as_float(b));
        if (!(f < 1.0f)) bad = 1;
    }
    unsigned long long m = __ballot(bad);
    if (lane == 0) flag[0] = (m == 0ULL) ? 1 : 0;
}

// ---------------- CSR build ----------------
__global__ void hist_kernel(const int* __restrict__ dst, int* __restrict__ row_ptr) {
    int e = blockIdx.x * blockDim.x + threadIdx.x;
    if (e < N_EDGES) atomicAdd(&row_ptr[dst[e] + 1], 1);
}

__global__ void scan_block(int* __restrict__ a, int* __restrict__ bsums) {
    __shared__ int sh[SCAN_BS];
    int gid = blockIdx.x * SCAN_BS + threadIdx.x;
    sh[threadIdx.x] = (gid < N_NODES) ? a[gid] : 0;
    __syncthreads();
    for (int off = 1; off < SCAN_BS; off <<= 1) {
        int t = (threadIdx.x >= off) ? sh[threadIdx.x - off] : 0;
        __syncthreads();
        sh[threadIdx.x] += t;
        __syncthreads();
    }
    if (gid < N_NODES) a[gid] = sh[threadIdx.x];
    if (threadIdx.x == SCAN_BS - 1) bsums[blockIdx.x] = sh[threadIdx.x];
}

__global__ void scan_tops(int* __restrict__ bsums) {
    __shared__ int sh[1024];
    sh[threadIdx.x] = (threadIdx.x < SCAN_NB) ? bsums[threadIdx.x] : 0;
    __syncthreads();
    for (int off = 1; off < 1024; off <<= 1) {
        int t = (threadIdx.x >= off) ? sh[threadIdx.x - off] : 0;
        __syncthreads();
        sh[threadIdx.x] += t;
        __syncthreads();
    }
    if (threadIdx.x < SCAN_NB) bsums[threadIdx.x] = sh[threadIdx.x];
}

// finalize row_ptr and init per-dst cursor (250k cursors -> no same-line atomic pileup)
__global__ void finalize_rows(int* __restrict__ row_ptr, const int* __restrict__ bsums,
                              int* __restrict__ cursor) {
    int i = blockIdx.x * blockDim.x + threadIdx.x;
    if (i >= N_NODES) return;
    int b = i / SCAN_BS;
    int v = row_ptr[i + 1];
    if (b > 0) v += bsums[b - 1];
    row_ptr[i + 1] = v;
    if (i + 1 < N_NODES) cursor[i + 1] = v;
    if (i == 0) { row_ptr[0] = 0; cursor[0] = 0; }
}

// round-3 shape: two independent 4B stores per edge (max MLP; best measured)
__global__ void scatter_kernel(const int* __restrict__ src, const int* __restrict__ dst,
                               const void* __restrict__ valsv, const int* __restrict__ flag,
                               int* __restrict__ cursor,
                               int* __restrict__ ssrc, float* __restrict__ sval) {
    int e = blockIdx.x * blockDim.x + threadIdx.x;
    if (e >= N_EDGES) return;
    int d = dst[e];
    int pos = atomicAdd(&cursor[d], 1);
    float v = (*flag) ? __bfloat162float(((const __hip_bfloat16*)valsv)[e])
                      : ((const float*)valsv)[e];
    ssrc[pos] = src[e];
    sval[pos] = v;
}

// ---------------- init: x(bf16) = concat(user,item); acc(fp32) or out-acc ----------------
__global__ void init_kernel(const void* __restrict__ uev, const void* __restrict__ iev,
                            const int* __restrict__ flag,
                            __hip_bfloat16* __restrict__ x,
                            float* __restrict__ acc,      // T1 (may be null)
                            void* __restrict__ outacc) {  // T2 (may be null)
    int i = blockIdx.x * blockDim.x + threadIdx.x;
    if (i >= N_ELEM) return;
    const int isbf = *flag;
    float v;
    if (i < U_ELEM) {
        v = isbf ? __bfloat162float(((const __hip_bfloat16*)uev)[i]) : ((const float*)uev)[i];
    } else {
        int j = i - U_ELEM;
        v = isbf ? __bfloat162float(((const __hip_bfloat16*)iev)[j]) : ((const float*)iev)[j];
    }
    x[i] = __float2bfloat16(v);
    if (acc) acc[i] = v;
    if (outacc) {
        if (isbf) ((__hip_bfloat16*)outacc)[i] = __float2bfloat16(0.25f * v);
        else      ((float*)outacc)[i]          = 0.25f * v;
    }
}

// ---------------- CSR SpMM: one wave per dst node, lane = dim; bf16 x, fp32 math ----------------
__global__ void spmm_csr(const int* __restrict__ row_ptr,
                         const int* __restrict__ ssrc,
                         const float* __restrict__ sval,
                         const __hip_bfloat16* __restrict__ x,
                         __hip_bfloat16* __restrict__ xn,
                         float* __restrict__ acc,      // T1 mode if non-null
                         void* __restrict__ outv,      // T2 RMW target, or T1 final target
                         const int* __restrict__ flag,
                         int last) {
    int lane = threadIdx.x & 63;
    int w = (blockIdx.x * blockDim.x + threadIdx.x) >> 6;
    if (w >= N_NODES) return;
    int beg = row_ptr[w], end = row_ptr[w + 1];
    float s0 = 0.f, s1 = 0.f, s2 = 0.f, s3 = 0.f;
    int e = beg;
    for (; e + 4 <= end; e += 4) {
        int i0 = ssrc[e], i1 = ssrc[e + 1], i2 = ssrc[e + 2], i3 = ssrc[e + 3];
        float v0 = sval[e],     v1 = sval[e + 1];
        float v2 = sval[e + 2], v3 = sval[e + 3];
        float a0 = __bfloat162float(x[(size_t)i0 * DIM + lane]);
        float a1 = __bfloat162float(x[(size_t)i1 * DIM + lane]);
        float a2 = __bfloat162float(x[(size_t)i2 * DIM + lane]);
        float a3 = __bfloat162float(x[(size_t)i3 * DIM + lane]);
        s0 += v0 * a0; s1 += v1 * a1; s2 += v2 * a2; s3 += v3 * a3;
    }
    for (; e < end; ++e)
        s0 += sval[e] * __bfloat162float(x[(size_t)ssrc[e] * DIM + lane]);
    float s = (s0 + s1) + (s2 + s3);

    size_t o = (size_t)w * DIM + lane;
    if (acc) {
        if (!last) {
            xn[o] = __float2bfloat16(s);
            acc[o] += s;
        } else {
            float r = 0.25f * (acc[o] + s);
            if (*flag) ((__hip_bfloat16*)outv)[o] = __float2bfloat16(r);
            else       ((float*)outv)[o]          = r;
        }
    } else {
        if (!last) xn[o] = __float2bfloat16(s);
        if (*flag) {
            __hip_bfloat16* ob = (__hip_bfloat16*)outv;
            ob[o] = __float2bfloat16(__bfloat162float(ob[o]) + 0.25f * s);
        } else {
            float* of = (float*)outv;
            of[o] += 0.25f * s;
        }
    }
}

// ---------------- host ----------------
static inline size_t align256(size_t x) { return (x + 255) & ~(size_t)255; }

extern "C" void kernel_launch(void* const* d_in, const int* in_sizes, int n_in,
                              void* d_out, int out_size, void* d_ws, size_t ws_size,
                              hipStream_t stream) {
    const int* es = (const int*)d_in[3];
    const int* ed = (const int*)d_in[4];

    char* wsb = (char*)d_ws;
    size_t off = 0;
    int*   flag    = (int*)wsb;               off = align256(off + sizeof(int));
    int*   row_ptr = (int*)(wsb + off);       off = align256(off + (size_t)(N_NODES + 1) * 4);
    int*   cursor  = (int*)(wsb + off);       off = align256(off + (size_t)N_NODES * 4);
    int*   bsums   = (int*)(wsb + off);       off = align256(off + (size_t)SCAN_NB * 4);
    int*   ssrc    = (int*)(wsb + off);       off = align256(off + (size_t)N_EDGES * 4);
    float* sval    = (float*)(wsb + off);     off = align256(off + (size_t)N_EDGES * 4);
    size_t buf_off = off;

    const size_t bfbuf  = (size_t)N_ELEM * sizeof(__hip_bfloat16); // 32 MB
    const size_t f32buf = (size_t)N_ELEM * sizeof(float);          // 64 MB

    const int eb = 256;
    const int egrid = (N_ELEM + eb - 1) / eb;
    const int ggrid = (N_EDGES + eb - 1) / eb;            // 15625
    const int ngrid = (N_NODES + eb - 1) / eb;            // 977
    const int sgrid = (N_NODES + 3) / 4;                  // 62500 blocks, 4 waves each

    // ---- prologue: probe + CSR build ----
    probe_dtype<<<1, 64, 0, stream>>>((const unsigned short*)d_in[0], flag);
    hipMemsetAsync(row_ptr, 0, (size_t)(N_NODES + 1) * 4, stream);
    hist_kernel<<<ggrid, eb, 0, stream>>>(ed, row_ptr);
    scan_block<<<SCAN_NB, SCAN_BS, 0, stream>>>(row_ptr + 1, bsums);
    scan_tops<<<1, 1024, 0, stream>>>(bsums);
    finalize_rows<<<ngrid, eb, 0, stream>>>(row_ptr, bsums, cursor);
    scatter_kernel<<<ggrid, eb, 0, stream>>>(es, ed, d_in[2], flag, cursor, ssrc, sval);

    size_t need_t1 = buf_off + 2 * bfbuf + f32buf;   // ~161 MB
    size_t need_t2 = buf_off + 2 * bfbuf;            // ~97 MB

    if (ws_size >= need_t1) {
        // T1: bf16 x, xn + fp32 acc; out written by last spmm
        __hip_bfloat16* x  = (__hip_bfloat16*)(wsb + buf_off);
        __hip_bfloat16* xn = x + N_ELEM;
        float* acc = (float*)(wsb + buf_off + 2 * bfbuf);
        init_kernel<<<egrid, eb, 0, stream>>>(d_in[0], d_in[1], flag, x, acc, nullptr);
        spmm_csr<<<sgrid, eb, 0, stream>>>(row_ptr, ssrc, sval, x,  xn, acc, nullptr, flag, 0);
        spmm_csr<<<sgrid, eb, 0, stream>>>(row_ptr, ssrc, sval, xn, x,  acc, nullptr, flag, 0);
        spmm_csr<<<sgrid, eb, 0, stream>>>(row_ptr, ssrc, sval, x,  xn, acc, d_out,   flag, 1);
    } else {
        // T2: bf16 x, xn; accumulate into d_out (RMW)
        __hip_bfloat16* x  = (__hip_bfloat16*)(wsb + buf_off);
        __hip_bfloat16* xn = x + N_ELEM;
        init_kernel<<<egrid, eb, 0, stream>>>(d_in[0], d_in[1], flag, x, nullptr, d_out);
        spmm_csr<<<sgrid, eb, 0, stream>>>(row_ptr, ssrc, sval, x,  xn, nullptr, d_out, flag, 0);
        spmm_csr<<<sgrid, eb, 0, stream>>>(row_ptr, ssrc, sval, xn, x,  nullptr, d_out, flag, 0);
        spmm_csr<<<sgrid, eb, 0, stream>>>(row_ptr, ssrc, sval, x,  xn, nullptr, d_out, flag, 1);
    }
}

// Round 7
// 832.908 us; speedup vs baseline: 2.1133x; 1.2918x over previous
//
#include <hip/hip_runtime.h>
#include <hip/hip_bf16.h>

#define N_USERS 100000
#define N_ITEMS 150000
#define N_NODES 250000
#define N_EDGES 4000000
#define DIM     64
#define N_ELEM  (N_NODES * DIM)      // 16,000,000
#define U_ELEM  (N_USERS * DIM)      //  6,400,000
#define BSHIFT  8
#define NBUCKET ((N_NODES + (1 << BSHIFT) - 1) >> BSHIFT)  // 977
#define NB_HIST 256
#define CHUNK   (N_EDGES / NB_HIST)  // 15625 (exact)

// ---------------- dtype probe (flag=1 -> bf16 inputs, 0 -> fp32) ----------------
__global__ void probe_dtype(const unsigned short* __restrict__ ue, int* __restrict__ flag) {
    int lane = threadIdx.x;   // 64 threads
    int bad = 0;
    #pragma unroll
    for (int k = 0; k < 8; ++k) {
        unsigned int b = ((unsigned int)ue[lane * 8 + k]) << 16;
        float f = fabsf(__uint_as_float(b));
        if (!(f < 1.0f)) bad = 1;
    }
    unsigned long long m = __ballot(bad);
    if (lane == 0) flag[0] = (m == 0ULL) ? 1 : 0;
}

// ---- stage 1: per-chunk LDS bucket histogram -> M[block][bucket] (no global atomics) ----
__global__ void hist_bucket(const int* __restrict__ dst, int* __restrict__ M) {
    __shared__ int h[NBUCKET];
    for (int b = threadIdx.x; b < NBUCKET; b += blockDim.x) h[b] = 0;
    __syncthreads();
    int base = blockIdx.x * CHUNK;
    for (int i = threadIdx.x; i < CHUNK; i += blockDim.x) {
        int e = base + i;
        if (e < N_EDGES) atomicAdd(&h[dst[e] >> BSHIFT], 1);
    }
    __syncthreads();
    for (int b = threadIdx.x; b < NBUCKET; b += blockDim.x)
        M[blockIdx.x * NBUCKET + b] = h[b];
}

// ---- stage 2: single block: bucket totals, bucket bases, per-(block,bucket) bases ----
__global__ void scan_small(int* __restrict__ M, int* __restrict__ bbase,
                           int* __restrict__ row_ptr) {
    __shared__ int sh[1024];
    int b = threadIdx.x;
    int tot = 0;
    if (b < NBUCKET)
        for (int k = 0; k < NB_HIST; ++k) tot += M[k * NBUCKET + b];
    sh[b] = (b < NBUCKET) ? tot : 0;
    __syncthreads();
    for (int off = 1; off < 1024; off <<= 1) {
        int t = (b >= off) ? sh[b - off] : 0;
        __syncthreads();
        sh[b] += t;
        __syncthreads();
    }
    if (b < NBUCKET) {
        int run = sh[b] - tot;             // exclusive bucket base
        bbase[b] = run;
        for (int k = 0; k < NB_HIST; ++k) {
            int t = M[k * NBUCKET + b];
            M[k * NBUCKET + b] = run;      // deterministic base for (block k, bucket b)
            run += t;
        }
    }
    if (b == 0) { bbase[NBUCKET] = N_EDGES; row_ptr[N_NODES] = N_EDGES; }
}

// ---- stage 3: deterministic bucket binning with LDS cursors (no global atomics) ----
__global__ void bin_scatter(const int* __restrict__ src, const int* __restrict__ dst,
                            const void* __restrict__ valsv, const int* __restrict__ flag,
                            const int* __restrict__ M, int2* __restrict__ aux) {
    __shared__ int cur[NBUCKET];
    for (int b = threadIdx.x; b < NBUCKET; b += blockDim.x)
        cur[b] = M[blockIdx.x * NBUCKET + b];
    __syncthreads();
    const int isbf = *flag;
    int base = blockIdx.x * CHUNK;
    for (int i = threadIdx.x; i < CHUNK; i += blockDim.x) {
        int e = base + i;
        if (e >= N_EDGES) break;
        int d = dst[e];
        int pos = atomicAdd(&cur[d >> BSHIFT], 1);   // LDS atomic, block-local
        float v = isbf ? __bfloat162float(((const __hip_bfloat16*)valsv)[e])
                       : ((const float*)valsv)[e];
        int2 r;
        r.x = src[e] | ((d & ((1 << BSHIFT) - 1)) << 18);  // src<2^18, dstlo in bits 18..25
        r.y = __float_as_int(v);
        aux[pos] = r;
    }
}

// ---- stage 4: one block per bucket: local CSR (row_ptr slice + ssrc/sval), all L2-local ----
__global__ void bucket_csr(const int* __restrict__ bbase, const int2* __restrict__ aux,
                           int* __restrict__ row_ptr, int* __restrict__ ssrc,
                           float* __restrict__ sval) {
    __shared__ int h[256];
    __shared__ int c[256];
    int b  = blockIdx.x;
    int n0 = b << BSHIFT;
    int nd = N_NODES - n0; if (nd > 256) nd = 256;
    int lo = bbase[b], hi = bbase[b + 1];
    int t = threadIdx.x;
    h[t] = 0;
    __syncthreads();
    for (int e = lo + t; e < hi; e += blockDim.x)
        atomicAdd(&h[(aux[e].x >> 18) & 255], 1);
    __syncthreads();
    int v = h[t];
    c[t] = v;
    __syncthreads();
    for (int off = 1; off < 256; off <<= 1) {
        int u = (t >= off) ? c[t - off] : 0;
        __syncthreads();
        c[t] += u;
        __syncthreads();
    }
    int gbase = lo + c[t] - v;            // exclusive prefix + bucket base
    if (t < nd) row_ptr[n0 + t] = gbase;
    c[t] = gbase;                         // reuse as cursor (own-slot write, no cross-read)
    __syncthreads();
    for (int e = lo + t; e < hi; e += blockDim.x) {
        int2 r = aux[e];
        int pos = atomicAdd(&c[(r.x >> 18) & 255], 1);
        ssrc[pos] = r.x & 0x3FFFF;
        sval[pos] = __int_as_float(r.y);
    }
}

// ---------------- init: x(bf16) = concat(user,item); acc(fp32) or out-acc ----------------
__global__ void init_kernel(const void* __restrict__ uev, const void* __restrict__ iev,
                            const int* __restrict__ flag,
                            __hip_bfloat16* __restrict__ x,
                            float* __restrict__ acc,      // T1 (may be null)
                            void* __restrict__ outacc) {  // T2 (may be null)
    int i = blockIdx.x * blockDim.x + threadIdx.x;
    if (i >= N_ELEM) return;
    const int isbf = *flag;
    float v;
    if (i < U_ELEM) {
        v = isbf ? __bfloat162float(((const __hip_bfloat16*)uev)[i]) : ((const float*)uev)[i];
    } else {
        int j = i - U_ELEM;
        v = isbf ? __bfloat162float(((const __hip_bfloat16*)iev)[j]) : ((const float*)iev)[j];
    }
    x[i] = __float2bfloat16(v);
    if (acc) acc[i] = v;
    if (outacc) {
        if (isbf) ((__hip_bfloat16*)outacc)[i] = __float2bfloat16(0.25f * v);
        else      ((float*)outacc)[i]          = 0.25f * v;
    }
}

// ---------------- CSR SpMM: one wave per dst node, lane = dim; unroll-8 ----------------
__global__ void spmm_csr(const int* __restrict__ row_ptr,
                         const int* __restrict__ ssrc,
                         const float* __restrict__ sval,
                         const __hip_bfloat16* __restrict__ x,
                         __hip_bfloat16* __restrict__ xn,
                         float* __restrict__ acc,      // T1 mode if non-null
                         void* __restrict__ outv,      // T2 RMW target, or T1 final target
                         const int* __restrict__ flag,
                         int last) {
    int lane = threadIdx.x & 63;
    int w = (blockIdx.x * blockDim.x + threadIdx.x) >> 6;
    if (w >= N_NODES) return;
    int beg = row_ptr[w], end = row_ptr[w + 1];
    float s0 = 0.f, s1 = 0.f, s2 = 0.f, s3 = 0.f;
    int e = beg;
    for (; e + 8 <= end; e += 8) {
        int i0 = ssrc[e],     i1 = ssrc[e + 1], i2 = ssrc[e + 2], i3 = ssrc[e + 3];
        int i4 = ssrc[e + 4], i5 = ssrc[e + 5], i6 = ssrc[e + 6], i7 = ssrc[e + 7];
        float v0 = sval[e],     v1 = sval[e + 1], v2 = sval[e + 2], v3 = sval[e + 3];
        float v4 = sval[e + 4], v5 = sval[e + 5], v6 = sval[e + 6], v7 = sval[e + 7];
        float a0 = __bfloat162float(x[(size_t)i0 * DIM + lane]);
        float a1 = __bfloat162float(x[(size_t)i1 * DIM + lane]);
        float a2 = __bfloat162float(x[(size_t)i2 * DIM + lane]);
        float a3 = __bfloat162float(x[(size_t)i3 * DIM + lane]);
        float a4 = __bfloat162float(x[(size_t)i4 * DIM + lane]);
        float a5 = __bfloat162float(x[(size_t)i5 * DIM + lane]);
        float a6 = __bfloat162float(x[(size_t)i6 * DIM + lane]);
        float a7 = __bfloat162float(x[(size_t)i7 * DIM + lane]);
        s0 += v0 * a0; s1 += v1 * a1; s2 += v2 * a2; s3 += v3 * a3;
        s0 += v4 * a4; s1 += v5 * a5; s2 += v6 * a6; s3 += v7 * a7;
    }
    for (; e + 4 <= end; e += 4) {
        int i0 = ssrc[e], i1 = ssrc[e + 1], i2 = ssrc[e + 2], i3 = ssrc[e + 3];
        float v0 = sval[e],     v1 = sval[e + 1];
        float v2 = sval[e + 2], v3 = sval[e + 3];
        float a0 = __bfloat162float(x[(size_t)i0 * DIM + lane]);
        float a1 = __bfloat162float(x[(size_t)i1 * DIM + lane]);
        float a2 = __bfloat162float(x[(size_t)i2 * DIM + lane]);
        float a3 = __bfloat162float(x[(size_t)i3 * DIM + lane]);
        s0 += v0 * a0; s1 += v1 * a1; s2 += v2 * a2; s3 += v3 * a3;
    }
    for (; e < end; ++e)
        s0 += sval[e] * __bfloat162float(x[(size_t)ssrc[e] * DIM + lane]);
    float s = (s0 + s1) + (s2 + s3);

    size_t o = (size_t)w * DIM + lane;
    if (acc) {
        if (!last) {
            xn[o] = __float2bfloat16(s);
            acc[o] += s;
        } else {
            float r = 0.25f * (acc[o] + s);
            if (*flag) ((__hip_bfloat16*)outv)[o] = __float2bfloat16(r);
            else       ((float*)outv)[o]          = r;
        }
    } else {
        if (!last) xn[o] = __float2bfloat16(s);
        if (*flag) {
            __hip_bfloat16* ob = (__hip_bfloat16*)outv;
            ob[o] = __float2bfloat16(__bfloat162float(ob[o]) + 0.25f * s);
        } else {
            float* of = (float*)outv;
            of[o] += 0.25f * s;
        }
    }
}

// ---------------- host ----------------
static inline size_t align256(size_t x) { return (x + 255) & ~(size_t)255; }

extern "C" void kernel_launch(void* const* d_in, const int* in_sizes, int n_in,
                              void* d_out, int out_size, void* d_ws, size_t ws_size,
                              hipStream_t stream) {
    const int* es = (const int*)d_in[3];
    const int* ed = (const int*)d_in[4];

    char* wsb = (char*)d_ws;
    size_t off = 0;
    int*   flag    = (int*)wsb;               off = align256(off + sizeof(int));
    int*   M       = (int*)(wsb + off);       off = align256(off + (size_t)NB_HIST * NBUCKET * 4);
    int*   bbase   = (int*)(wsb + off);       off = align256(off + (size_t)(NBUCKET + 1) * 4);
    int*   row_ptr = (int*)(wsb + off);       off = align256(off + (size_t)(N_NODES + 1) * 4);
    int*   ssrc    = (int*)(wsb + off);       off = align256(off + (size_t)N_EDGES * 4);
    float* sval    = (float*)(wsb + off);     off = align256(off + (size_t)N_EDGES * 4);
    size_t z_off = off;
    // aux (32 MB) aliases x: binB consumes aux before init writes x (stream-ordered).
    int2* aux = (int2*)(wsb + z_off);

    const size_t bfbuf  = (size_t)N_ELEM * sizeof(__hip_bfloat16); // 32 MB
    const size_t f32buf = (size_t)N_ELEM * sizeof(float);          // 64 MB

    const int eb = 256;
    const int egrid = (N_ELEM + eb - 1) / eb;
    const int sgrid = (N_NODES + 3) / 4;                  // 62500 blocks, 4 waves each

    // ---- build: probe + deterministic two-pass binning (no global atomics) ----
    probe_dtype<<<1, 64, 0, stream>>>((const unsigned short*)d_in[0], flag);
    hist_bucket<<<NB_HIST, eb, 0, stream>>>(ed, M);
    scan_small<<<1, 1024, 0, stream>>>(M, bbase, row_ptr);
    bin_scatter<<<NB_HIST, eb, 0, stream>>>(es, ed, d_in[2], flag, M, aux);
    bucket_csr<<<NBUCKET, eb, 0, stream>>>(bbase, aux, row_ptr, ssrc, sval);

    size_t need_t1 = z_off + 2 * bfbuf + f32buf;   // ~162 MB
    // T2 fallback: ~98 MB

    if (ws_size >= need_t1) {
        // T1: bf16 x, xn + fp32 acc; out written by last spmm
        __hip_bfloat16* x  = (__hip_bfloat16*)(wsb + z_off);
        __hip_bfloat16* xn = x + N_ELEM;
        float* acc = (float*)(wsb + z_off + 2 * bfbuf);
        init_kernel<<<egrid, eb, 0, stream>>>(d_in[0], d_in[1], flag, x, acc, nullptr);
        spmm_csr<<<sgrid, eb, 0, stream>>>(row_ptr, ssrc, sval, x,  xn, acc, nullptr, flag, 0);
        spmm_csr<<<sgrid, eb, 0, stream>>>(row_ptr, ssrc, sval, xn, x,  acc, nullptr, flag, 0);
        spmm_csr<<<sgrid, eb, 0, stream>>>(row_ptr, ssrc, sval, x,  xn, acc, d_out,   flag, 1);
    } else {
        // T2: bf16 x, xn; accumulate into d_out (RMW)
        __hip_bfloat16* x  = (__hip_bfloat16*)(wsb + z_off);
        __hip_bfloat16* xn = x + N_ELEM;
        init_kernel<<<egrid, eb, 0, stream>>>(d_in[0], d_in[1], flag, x, nullptr, d_out);
        spmm_csr<<<sgrid, eb, 0, stream>>>(row_ptr, ssrc, sval, x,  xn, nullptr, d_out, flag, 0);
        spmm_csr<<<sgrid, eb, 0, stream>>>(row_ptr, ssrc, sval, xn, x,  nullptr, d_out, flag, 0);
        spmm_csr<<<sgrid, eb, 0, stream>>>(row_ptr, ssrc, sval, x,  xn, nullptr, d_out, flag, 1);
    }
}

// Round 8
// 784.079 us; speedup vs baseline: 2.2449x; 1.0623x over previous
//
#include <hip/hip_runtime.h>
#include <hip/hip_bf16.h>

#define N_USERS 100000
#define N_ITEMS 150000
#define N_NODES 250000
#define N_EDGES 4000000
#define DIM     64
#define N_ELEM  (N_NODES * DIM)      // 16,000,000
#define U_ELEM  (N_USERS * DIM)      //  6,400,000
#define BSHIFT  8
#define NBUCKET ((N_NODES + (1 << BSHIFT) - 1) >> BSHIFT)  // 977
#define NB_HIST 256
#define CHUNK   (N_EDGES / NB_HIST)  // 15625 (exact)

// ---------------- dtype probe (flag=1 -> bf16 inputs, 0 -> fp32) ----------------
__global__ void probe_dtype(const unsigned short* __restrict__ ue, int* __restrict__ flag) {
    int lane = threadIdx.x;   // 64 threads
    int bad = 0;
    #pragma unroll
    for (int k = 0; k < 8; ++k) {
        unsigned int b = ((unsigned int)ue[lane * 8 + k]) << 16;
        float f = fabsf(__uint_as_float(b));
        if (!(f < 1.0f)) bad = 1;
    }
    unsigned long long m = __ballot(bad);
    if (lane == 0) flag[0] = (m == 0ULL) ? 1 : 0;
}

// ---- stage 1: per-chunk LDS bucket histogram -> M[block][bucket] ----
__global__ void hist_bucket(const int* __restrict__ dst, int* __restrict__ M) {
    __shared__ int h[NBUCKET];
    for (int b = threadIdx.x; b < NBUCKET; b += blockDim.x) h[b] = 0;
    __syncthreads();
    int base = blockIdx.x * CHUNK;
    for (int i = threadIdx.x; i < CHUNK; i += blockDim.x) {
        int e = base + i;
        if (e < N_EDGES) atomicAdd(&h[dst[e] >> BSHIFT], 1);
    }
    __syncthreads();
    for (int b = threadIdx.x; b < NBUCKET; b += blockDim.x)
        M[blockIdx.x * NBUCKET + b] = h[b];
}

// ---- stage 2: single block: bucket bases + per-(block,bucket) bases ----
__global__ void scan_small(int* __restrict__ M, int* __restrict__ bbase,
                           int* __restrict__ row_ptr) {
    __shared__ int sh[1024];
    int b = threadIdx.x;
    int tot = 0;
    if (b < NBUCKET)
        for (int k = 0; k < NB_HIST; ++k) tot += M[k * NBUCKET + b];
    sh[b] = (b < NBUCKET) ? tot : 0;
    __syncthreads();
    for (int off = 1; off < 1024; off <<= 1) {
        int t = (b >= off) ? sh[b - off] : 0;
        __syncthreads();
        sh[b] += t;
        __syncthreads();
    }
    if (b < NBUCKET) {
        int run = sh[b] - tot;             // exclusive bucket base
        bbase[b] = run;
        for (int k = 0; k < NB_HIST; ++k) {
            int t = M[k * NBUCKET + b];
            M[k * NBUCKET + b] = run;      // deterministic base for (block k, bucket b)
            run += t;
        }
    }
    if (b == 0) { bbase[NBUCKET] = N_EDGES; row_ptr[N_NODES] = N_EDGES; }
}

// ---- stage 3: deterministic bucket binning with LDS cursors ----
__global__ void bin_scatter(const int* __restrict__ src, const int* __restrict__ dst,
                            const void* __restrict__ valsv, const int* __restrict__ flag,
                            const int* __restrict__ M, int2* __restrict__ aux) {
    __shared__ int cur[NBUCKET];
    for (int b = threadIdx.x; b < NBUCKET; b += blockDim.x)
        cur[b] = M[blockIdx.x * NBUCKET + b];
    __syncthreads();
    const int isbf = *flag;
    int base = blockIdx.x * CHUNK;
    for (int i = threadIdx.x; i < CHUNK; i += blockDim.x) {
        int e = base + i;
        if (e >= N_EDGES) break;
        int d = dst[e];
        int pos = atomicAdd(&cur[d >> BSHIFT], 1);   // LDS atomic, block-local
        float v = isbf ? __bfloat162float(((const __hip_bfloat16*)valsv)[e])
                       : ((const float*)valsv)[e];
        int2 r;
        r.x = src[e] | ((d & ((1 << BSHIFT) - 1)) << 18);  // src<2^18, dstlo in bits 18..25
        r.y = __float_as_int(v);
        aux[pos] = r;
    }
}

// ---- stage 4: one block per bucket: row_ptr slice + packed sedge, all L2-local ----
__global__ void bucket_csr(const int* __restrict__ bbase, const int2* __restrict__ aux,
                           int* __restrict__ row_ptr, int2* __restrict__ sedge) {
    __shared__ int h[256];
    __shared__ int c[256];
    int b  = blockIdx.x;
    int n0 = b << BSHIFT;
    int nd = N_NODES - n0; if (nd > 256) nd = 256;
    int lo = bbase[b], hi = bbase[b + 1];
    int t = threadIdx.x;
    h[t] = 0;
    __syncthreads();
    for (int e = lo + t; e < hi; e += blockDim.x)
        atomicAdd(&h[(aux[e].x >> 18) & 255], 1);
    __syncthreads();
    int v = h[t];
    c[t] = v;
    __syncthreads();
    for (int off = 1; off < 256; off <<= 1) {
        int u = (t >= off) ? c[t - off] : 0;
        __syncthreads();
        c[t] += u;
        __syncthreads();
    }
    int gbase = lo + c[t] - v;            // exclusive prefix + bucket base
    if (t < nd) row_ptr[n0 + t] = gbase;
    c[t] = gbase;                         // reuse as cursor
    __syncthreads();
    for (int e = lo + t; e < hi; e += blockDim.x) {
        int2 r = aux[e];
        int pos = atomicAdd(&c[(r.x >> 18) & 255], 1);
        int2 o; o.x = r.x & 0x3FFFF; o.y = r.y;
        sedge[pos] = o;
    }
}

// ---------------- init: x0(bf16) = concat(user,item); T2 also seeds out ----------------
__global__ void init_kernel(const void* __restrict__ uev, const void* __restrict__ iev,
                            const int* __restrict__ flag,
                            __hip_bfloat16* __restrict__ x,
                            void* __restrict__ outacc) {  // T2 only (may be null)
    int i = blockIdx.x * blockDim.x + threadIdx.x;
    if (i >= N_ELEM) return;
    const int isbf = *flag;
    float v;
    if (i < U_ELEM) {
        v = isbf ? __bfloat162float(((const __hip_bfloat16*)uev)[i]) : ((const float*)uev)[i];
    } else {
        int j = i - U_ELEM;
        v = isbf ? __bfloat162float(((const __hip_bfloat16*)iev)[j]) : ((const float*)iev)[j];
    }
    x[i] = __float2bfloat16(v);
    if (outacc) {
        if (isbf) ((__hip_bfloat16*)outacc)[i] = __float2bfloat16(0.25f * v);
        else      ((float*)outacc)[i]          = 0.25f * v;
    }
}

// ---------------- CSR SpMM: one wave per dst node, lane = dim; unroll-8 ----------------
// MODE 0: T1 mid   -> xn = bf16(s)
// MODE 1: T1 last  -> out = 0.25*(x0+x1+x2+s)
// MODE 2: T2 mid   -> xn = bf16(s); out += 0.25*s (RMW)
// MODE 3: T2 last  -> out += 0.25*s (RMW)
template <int MODE>
__global__ void spmm_csr(const int* __restrict__ row_ptr,
                         const int2* __restrict__ sedge,
                         const __hip_bfloat16* __restrict__ x,
                         __hip_bfloat16* __restrict__ xn,
                         const __hip_bfloat16* __restrict__ p0,
                         const __hip_bfloat16* __restrict__ p1,
                         void* __restrict__ outv,
                         const int* __restrict__ flag) {
    int lane = threadIdx.x & 63;
    int w = (blockIdx.x * blockDim.x + threadIdx.x) >> 6;
    if (w >= N_NODES) return;
    int beg = row_ptr[w], end = row_ptr[w + 1];
    float s0 = 0.f, s1 = 0.f, s2 = 0.f, s3 = 0.f;
    int e = beg;
    for (; e + 8 <= end; e += 8) {
        int2 r0 = sedge[e],     r1 = sedge[e + 1], r2 = sedge[e + 2], r3 = sedge[e + 3];
        int2 r4 = sedge[e + 4], r5 = sedge[e + 5], r6 = sedge[e + 6], r7 = sedge[e + 7];
        float a0 = __bfloat162float(x[(size_t)r0.x * DIM + lane]);
        float a1 = __bfloat162float(x[(size_t)r1.x * DIM + lane]);
        float a2 = __bfloat162float(x[(size_t)r2.x * DIM + lane]);
        float a3 = __bfloat162float(x[(size_t)r3.x * DIM + lane]);
        float a4 = __bfloat162float(x[(size_t)r4.x * DIM + lane]);
        float a5 = __bfloat162float(x[(size_t)r5.x * DIM + lane]);
        float a6 = __bfloat162float(x[(size_t)r6.x * DIM + lane]);
        float a7 = __bfloat162float(x[(size_t)r7.x * DIM + lane]);
        s0 += __int_as_float(r0.y) * a0; s1 += __int_as_float(r1.y) * a1;
        s2 += __int_as_float(r2.y) * a2; s3 += __int_as_float(r3.y) * a3;
        s0 += __int_as_float(r4.y) * a4; s1 += __int_as_float(r5.y) * a5;
        s2 += __int_as_float(r6.y) * a6; s3 += __int_as_float(r7.y) * a7;
    }
    for (; e + 4 <= end; e += 4) {
        int2 r0 = sedge[e], r1 = sedge[e + 1], r2 = sedge[e + 2], r3 = sedge[e + 3];
        float a0 = __bfloat162float(x[(size_t)r0.x * DIM + lane]);
        float a1 = __bfloat162float(x[(size_t)r1.x * DIM + lane]);
        float a2 = __bfloat162float(x[(size_t)r2.x * DIM + lane]);
        float a3 = __bfloat162float(x[(size_t)r3.x * DIM + lane]);
        s0 += __int_as_float(r0.y) * a0; s1 += __int_as_float(r1.y) * a1;
        s2 += __int_as_float(r2.y) * a2; s3 += __int_as_float(r3.y) * a3;
    }
    for (; e < end; ++e) {
        int2 r = sedge[e];
        s0 += __int_as_float(r.y) * __bfloat162float(x[(size_t)r.x * DIM + lane]);
    }
    float s = (s0 + s1) + (s2 + s3);

    size_t o = (size_t)w * DIM + lane;
    if (MODE == 0) {
        xn[o] = __float2bfloat16(s);
    } else if (MODE == 1) {
        float r = 0.25f * (s + __bfloat162float(p0[o]) + __bfloat162float(p1[o])
                             + __bfloat162float(x[o]));   // x == x2 here
        if (*flag) ((__hip_bfloat16*)outv)[o] = __float2bfloat16(r);
        else       ((float*)outv)[o]          = r;
    } else if (MODE == 2) {
        xn[o] = __float2bfloat16(s);
        if (*flag) {
            __hip_bfloat16* ob = (__hip_bfloat16*)outv;
            ob[o] = __float2bfloat16(__bfloat162float(ob[o]) + 0.25f * s);
        } else {
            float* of = (float*)outv;
            of[o] += 0.25f * s;
        }
    } else {
        if (*flag) {
            __hip_bfloat16* ob = (__hip_bfloat16*)outv;
            ob[o] = __float2bfloat16(__bfloat162float(ob[o]) + 0.25f * s);
        } else {
            float* of = (float*)outv;
            of[o] += 0.25f * s;
        }
    }
}

// ---------------- host ----------------
static inline size_t align256(size_t x) { return (x + 255) & ~(size_t)255; }

extern "C" void kernel_launch(void* const* d_in, const int* in_sizes, int n_in,
                              void* d_out, int out_size, void* d_ws, size_t ws_size,
                              hipStream_t stream) {
    const int* es = (const int*)d_in[3];
    const int* ed = (const int*)d_in[4];

    char* wsb = (char*)d_ws;
    size_t off = 0;
    int*  flag    = (int*)wsb;               off = align256(off + sizeof(int));
    int*  M       = (int*)(wsb + off);       off = align256(off + (size_t)NB_HIST * NBUCKET * 4);
    int*  bbase   = (int*)(wsb + off);       off = align256(off + (size_t)(NBUCKET + 1) * 4);
    int*  row_ptr = (int*)(wsb + off);       off = align256(off + (size_t)(N_NODES + 1) * 4);
    int2* sedge   = (int2*)(wsb + off);      off = align256(off + (size_t)N_EDGES * 8);
    size_t z_off = off;
    // aux (32 MB) aliases x0: bucket_csr consumes aux before init writes x0.
    int2* aux = (int2*)(wsb + z_off);

    const size_t bfbuf = (size_t)N_ELEM * sizeof(__hip_bfloat16); // 32 MB

    const int eb = 256;
    const int egrid = (N_ELEM + eb - 1) / eb;
    const int sgrid = (N_NODES + 3) / 4;                  // 62500 blocks, 4 waves each

    // ---- build: probe + deterministic two-pass binning (no global atomics) ----
    probe_dtype<<<1, 64, 0, stream>>>((const unsigned short*)d_in[0], flag);
    hist_bucket<<<NB_HIST, eb, 0, stream>>>(ed, M);
    scan_small<<<1, 1024, 0, stream>>>(M, bbase, row_ptr);
    bin_scatter<<<NB_HIST, eb, 0, stream>>>(es, ed, d_in[2], flag, M, aux);
    bucket_csr<<<NBUCKET, eb, 0, stream>>>(bbase, aux, row_ptr, sedge);

    size_t need_t1 = z_off + 3 * bfbuf;   // ~130 MB

    if (ws_size >= need_t1) {
        // T1: bf16 x0,x1,x2; last spmm fuses the 4-term average into d_out
        __hip_bfloat16* x0 = (__hip_bfloat16*)(wsb + z_off);
        __hip_bfloat16* x1 = x0 + N_ELEM;
        __hip_bfloat16* x2 = x1 + N_ELEM;
        init_kernel<<<egrid, eb, 0, stream>>>(d_in[0], d_in[1], flag, x0, nullptr);
        spmm_csr<0><<<sgrid, eb, 0, stream>>>(row_ptr, sedge, x0, x1, nullptr, nullptr, nullptr, flag);
        spmm_csr<0><<<sgrid, eb, 0, stream>>>(row_ptr, sedge, x1, x2, nullptr, nullptr, nullptr, flag);
        spmm_csr<1><<<sgrid, eb, 0, stream>>>(row_ptr, sedge, x2, nullptr, x0, x1, d_out, flag);
    } else {
        // T2: bf16 x, xn; accumulate into d_out (RMW)
        __hip_bfloat16* x  = (__hip_bfloat16*)(wsb + z_off);
        __hip_bfloat16* xn = x + N_ELEM;
        init_kernel<<<egrid, eb, 0, stream>>>(d_in[0], d_in[1], flag, x, d_out);
        spmm_csr<2><<<sgrid, eb, 0, stream>>>(row_ptr, sedge, x,  xn, nullptr, nullptr, d_out, flag);
        spmm_csr<2><<<sgrid, eb, 0, stream>>>(row_ptr, sedge, xn, x,  nullptr, nullptr, d_out, flag);
        spmm_csr<3><<<sgrid, eb, 0, stream>>>(row_ptr, sedge, x,  nullptr, nullptr, nullptr, d_out, flag);
    }
}